// Round 11
// baseline (225.922 us; speedup 1.0000x reference)
//
#include <hip/hip_runtime.h>

#define NDIM 4096
#define B_LG 256
#define B_SM 256
#define N_WID 128
#define R_LG 64
#define R_SM 16
#define BLOCK 256
#define MAXB 256
#define OUT_SIZE (B_LG * R_LG + B_SM * R_SM)

// ws layout (ints): [0] n_items | [16..) items (8 ints each, <=1152) |
//   [16384..) large buckets 128*256 | [49152..) small buckets 128*256
#define ITEM_BASE 16
#define ITEM_STRIDE 8
#define WS_BKT_L 16384
#define WS_BKT_S 49152
#define GRID_MAIN 1152     // >= worst-case item count (768 large + 384 small)

typedef float floatv4 __attribute__((ext_vector_type(4)));

// ---- kernel 1: bucket by wid, build (wid, batch-pair, chunk) worklist ------
__global__ __launch_bounds__(256)
void setup_kernel(const int* __restrict__ wids_l,
                  const int* __restrict__ wids_s,
                  int* __restrict__ ws,
                  float* __restrict__ out)
{
    __shared__ int cnt[256];   // [0,128) large wid counts, [128,256) small
    __shared__ int sc[256];
    const int t = threadIdx.x;
    cnt[t] = 0;
    __syncthreads();
    {
        const int w = wids_l[t];
        const int s = atomicAdd(&cnt[w], 1);
        ws[WS_BKT_L + w * MAXB + s] = t;
        const int w2 = wids_s[t];
        const int s2 = atomicAdd(&cnt[128 + w2], 1);
        ws[WS_BKT_S + w2 * MAXB + s2] = t;
    }
    __syncthreads();
    // items for this wid-class: ceil(c/2) batch-pairs x chunks
    const int c      = cnt[t];
    const int chunks = (t < 128) ? 4 : 2;   // large: d-quarters, small: d-halves
    const int groups = (c + 1) >> 1;
    const int nit    = groups * chunks;
    sc[t] = nit;
    __syncthreads();
    for (int off = 1; off < 256; off <<= 1) {   // inclusive scan
        const int v = (t >= off) ? sc[t - off] : 0;
        __syncthreads();
        sc[t] += v;
        __syncthreads();
    }
    const int base = sc[t] - nit;               // exclusive prefix
    const int cls  = t >> 7;
    const int wid  = t & 127;
    const int* bkt = ws + ((cls == 0) ? (WS_BKT_L + wid * MAXB)
                                      : (WS_BKT_S + wid * MAXB));
    for (int g = 0; g < groups; ++g) {
        const int b0 = bkt[2 * g];
        const int b1 = (2 * g + 1 < c) ? bkt[2 * g + 1] : -1;
        for (int ch = 0; ch < chunks; ++ch) {
            int* it = ws + ITEM_BASE + (base + g * chunks + ch) * ITEM_STRIDE;
            it[0] = cls; it[1] = wid; it[2] = b0; it[3] = b1; it[4] = ch;
        }
    }
    if (t == 255) ws[0] = sc[255];
    for (int i = t; i < OUT_SIZE; i += 256) out[i] = 0.0f;
}

// ---- kernel 2: one block per worklist item ---------------------------------
// Streams DROWS rows of A[wid] once in ONE uninterrupted fully-unrolled loop
// (64 sequential 16B loads/wave for large, 32 for small -> high queue
// residency), fusing M<=2 batches. Partials combine via atomicAdd.
template<int R, int M, int DROWS>
__device__ __forceinline__ void gemv_item(
    const float* __restrict__ x,      // x rows base for this class
    const float* __restrict__ Ab,     // A[wid]
    float* __restrict__ outb,         // out base for this class
    int b0, int b1, int d0,
    float* __restrict__ xs,           // LDS >= M*DROWS floats
    float* __restrict__ red)          // LDS [4][16][4]
{
    constexpr int LPR  = R / 4;        // 16 (R=64) or 4 (R=16)
    constexpr int ROWS = BLOCK / LPR;  // 16 or 64
    constexpr int IT   = DROWS / ROWS; // 64 (large) or 32 (small)
    constexpr int UN   = 8;
    constexpr int NG   = IT / UN;      // 8 or 4

    const int t = threadIdx.x;
    const int rows[2] = {b0, b1};

#pragma unroll
    for (int m = 0; m < M; ++m)
        for (int i = t; i < DROWS / 4; i += BLOCK)
            reinterpret_cast<float4*>(xs + m * DROWS)[i] =
                reinterpret_cast<const float4*>(x + (size_t)rows[m] * NDIM + d0)[i];
    __syncthreads();   // the only barrier before the K-loop

    const int d_sub  = t / LPR;
    const int r_base = (t % LPR) * 4;
    const float* Abt = Ab + ((size_t)d0 + d_sub) * R + r_base;

    float acc[M][4];
#pragma unroll
    for (int m = 0; m < M; ++m)
#pragma unroll
        for (int j = 0; j < 4; ++j) acc[m][j] = 0.0f;

#pragma unroll
    for (int g = 0; g < NG; ++g) {
        floatv4 buf[UN];
#pragma unroll
        for (int p = 0; p < UN; ++p)
            buf[p] = __builtin_nontemporal_load(
                reinterpret_cast<const floatv4*>(Abt + (size_t)(g * UN + p) * ROWS * R));
#pragma unroll
        for (int p = 0; p < UN; ++p) {
            const int d = (g * UN + p) * ROWS + d_sub;
#pragma unroll
            for (int m = 0; m < M; ++m) {
                const float xv = xs[m * DROWS + d];
                acc[m][0] = fmaf(xv, buf[p].x, acc[m][0]);
                acc[m][1] = fmaf(xv, buf[p].y, acc[m][1]);
                acc[m][2] = fmaf(xv, buf[p].z, acc[m][2]);
                acc[m][3] = fmaf(xv, buf[p].w, acc[m][3]);
            }
        }
    }

    const int wave = t >> 6;
    const int lane = t & 63;
#pragma unroll
    for (int m = 0; m < M; ++m)
#pragma unroll
        for (int off = 32; off >= LPR; off >>= 1)
#pragma unroll
            for (int j = 0; j < 4; ++j)
                acc[m][j] += __shfl_down(acc[m][j], off, 64);

#pragma unroll
    for (int m = 0; m < M; ++m) {
        __syncthreads();
        if (lane < LPR)
#pragma unroll
            for (int j = 0; j < 4; ++j) red[(wave * 16 + lane) * 4 + j] = acc[m][j];
        __syncthreads();
        if (t < R) {
            const int rl = t / 4, j = t % 4;
            float v = 0.0f;
#pragma unroll
            for (int w = 0; w < 4; ++w) v += red[(w * 16 + rl) * 4 + j];
            atomicAdd(outb + (size_t)rows[m] * R + t, v);
        }
    }
}

__global__ __launch_bounds__(BLOCK, 4)
void SequentialLoraA_kernel(const float* __restrict__ x,
                            const float* __restrict__ Al,
                            const float* __restrict__ As,
                            float* __restrict__ out,
                            const int* __restrict__ ws)
{
    __shared__ float xs[2 * 2048];     // 16 KB (large: 2x1024, small: 2x2048)
    __shared__ float red[4 * 16 * 4];  // 1 KB

    const int n = ws[0];
    if ((int)blockIdx.x >= n) return;
    const int* it = ws + ITEM_BASE + blockIdx.x * ITEM_STRIDE;
    const int cls = it[0], wid = it[1], b0 = it[2], b1 = it[3], ch = it[4];

    if (cls == 0) {
        const float* Ab = Al + (size_t)wid * NDIM * R_LG;
        const int d0 = ch * 1024;
        if (b1 < 0) gemv_item<R_LG, 1, 1024>(x, Ab, out, b0, b0, d0, xs, red);
        else        gemv_item<R_LG, 2, 1024>(x, Ab, out, b0, b1, d0, xs, red);
    } else {
        const float* Ab = As + (size_t)wid * NDIM * R_SM;
        const int d0 = ch * 2048;
        const float* xb = x + (size_t)B_LG * NDIM;
        float* ob = out + (size_t)B_LG * R_LG;
        if (b1 < 0) gemv_item<R_SM, 1, 2048>(xb, Ab, ob, b0, b0, d0, xs, red);
        else        gemv_item<R_SM, 2, 2048>(xb, Ab, ob, b0, b1, d0, xs, red);
    }
}

extern "C" void kernel_launch(void* const* d_in, const int* in_sizes, int n_in,
                              void* d_out, int out_size, void* d_ws, size_t ws_size,
                              hipStream_t stream) {
    const float* x      = (const float*)d_in[0];
    const int*   wids_l = (const int*)d_in[1];
    const int*   wids_s = (const int*)d_in[2];
    const float* Al     = (const float*)d_in[3];
    const float* As     = (const float*)d_in[4];
    float* out = (float*)d_out;
    int*   ws  = (int*)d_ws;

    setup_kernel<<<1, 256, 0, stream>>>(wids_l, wids_s, ws, out);
    SequentialLoraA_kernel<<<GRID_MAIN, BLOCK, 0, stream>>>(x, Al, As, out, ws);
}